// Round 4
// baseline (3329.995 us; speedup 1.0000x reference)
//
#include <hip/hip_runtime.h>
#include <hip/hip_bf16.h>
#include <stdint.h>

// ---------------------------------------------------------------------------
// GraphEncoder. Round 4: 3-phase persistent scan (hW2 folded into stage A,
// x recomputed redundantly per block in stage D) + all-to-all FLAG barrier
// (no serialized RMWs on one line). Fits in the proven ~105.8 MB footprint.
// ---------------------------------------------------------------------------

typedef __bf16 bf16_t;
typedef __bf16 bf16x8 __attribute__((ext_vector_type(8)));
typedef float  f32x4  __attribute__((ext_vector_type(4)));

#define MFMA16(a,b,c) __builtin_amdgcn_mfma_f32_16x16x32_bf16((a),(b),(c),0,0,0)

// ---- workspace layout (bytes) ----
static constexpr size_t OFF_MEM  = 0;                       // bf16 [1536][64][512]
static constexpr size_t OFF_WALL = 100663296;               // bf16 [2560][512]  W_in;W_hh;Wh2
static constexpr size_t OFF_WC   = OFF_WALL + 2621440;      // bf16 [512][512]   W_out[:, :512]
static constexpr size_t OFF_WI   = OFF_WC + 524288;         // bf16 [1536][512]  W_ih
static constexpr size_t OFF_LEN  = OFF_WI + 1572864;        // int [1536]
static constexpr size_t OFF_H    = OFF_LEN + 8192;          // f32 [32][512]
static constexpr size_t OFF_HBF  = OFF_H + 65536;           // bf16 [32][512]
static constexpr size_t OFF_Q    = OFF_HBF + 32768;         // bf16 [32][512]
static constexpr size_t OFF_GH   = OFF_Q + 32768;           // f32 [32][1536]
static constexpr size_t OFF_HW2  = OFF_GH + 196608;         // f32 [32][512]
static constexpr size_t OFF_CB   = OFF_HW2 + 65536;         // bf16 [32][512]
static constexpr size_t OFF_FLG  = OFF_CB + 32768;          // u32[32] flags
static constexpr size_t WS_NEED  = OFF_FLG + 128;           // = 105,816,192

// ---- helpers ----
__device__ __forceinline__ unsigned ld_a32(const void* p) {
  return __hip_atomic_load((const unsigned*)p, __ATOMIC_RELAXED, __HIP_MEMORY_SCOPE_AGENT);
}
__device__ __forceinline__ unsigned long long ld_a64(const void* p) {
  return __hip_atomic_load((const unsigned long long*)p, __ATOMIC_RELAXED, __HIP_MEMORY_SCOPE_AGENT);
}
__device__ __forceinline__ void st_a32(void* p, unsigned v) {
  __hip_atomic_store((unsigned*)p, v, __ATOMIC_RELAXED, __HIP_MEMORY_SCOPE_AGENT);
}
__device__ __forceinline__ void st_b16(void* p, __bf16 v) {
  __hip_atomic_store((unsigned short*)p, __builtin_bit_cast(unsigned short, v),
                     __ATOMIC_RELAXED, __HIP_MEMORY_SCOPE_AGENT);
}
__device__ __forceinline__ float u2f(unsigned u) { return __builtin_bit_cast(float, u); }
__device__ __forceinline__ unsigned f2u(float f) { return __builtin_bit_cast(unsigned, f); }
__device__ __forceinline__ float2 bf2f(unsigned u) {
  float2 r;
  unsigned lo = u << 16, hi = u & 0xffff0000u;
  r.x = __builtin_bit_cast(float, lo);
  r.y = __builtin_bit_cast(float, hi);
  return r;
}
__device__ __forceinline__ unsigned pack_bf2(float a, float b) {
  __bf16 ba = (__bf16)a, bb = (__bf16)b;
  unsigned short ua = __builtin_bit_cast(unsigned short, ba);
  unsigned short ub = __builtin_bit_cast(unsigned short, bb);
  return (unsigned)ua | ((unsigned)ub << 16);
}
__device__ __forceinline__ bf16x8 cvt8(float4 lo, float4 hi) {
  bf16x8 v;
  v[0]=(__bf16)lo.x; v[1]=(__bf16)lo.y; v[2]=(__bf16)lo.z; v[3]=(__bf16)lo.w;
  v[4]=(__bf16)hi.x; v[5]=(__bf16)hi.y; v[6]=(__bf16)hi.z; v[7]=(__bf16)hi.w;
  return v;
}
__device__ __forceinline__ float fsig(float x) {
  return __builtin_amdgcn_rcpf(1.f + __expf(-x));
}
__device__ __forceinline__ float ftanh(float x) {
  float e = __expf(-2.f * fabsf(x));
  float t = (1.f - e) * __builtin_amdgcn_rcpf(1.f + e);
  return __builtin_copysignf(t, x);
}
// All-to-all flag barrier: block stores its phase to its own word; wave 0
// polls all 32 flags with one coalesced sc1 load + ballot. No RMWs.
__device__ __forceinline__ void gbar(unsigned* flags, unsigned ph) {
  __syncthreads();   // drains vmcnt(0): all data stores at coherence point
  if (threadIdx.x < 64) {
    if (threadIdx.x == 0) st_a32(flags + blockIdx.x, ph);
    unsigned long long done;
    do {
      unsigned f = ld_a32(flags + (threadIdx.x & 31));
      done = __ballot(f >= ph);
    } while (done != ~0ull);
  }
  __syncthreads();
}

// ======================= prep kernels ======================================
__global__ __launch_bounds__(256) void prep_weights(
    const float* __restrict__ Win, const float* __restrict__ Whh,
    const float* __restrict__ Wout, const float* __restrict__ Wih,
    bf16_t* __restrict__ WALL, bf16_t* __restrict__ WC, bf16_t* __restrict__ WI)
{
  int idx = blockIdx.x * 256 + threadIdx.x;   // 2,359,296 total
  if (idx < 1310720) {
    int r = idx >> 9, k = idx & 511;
    float v;
    if (r < 512)       v = Win[r*512 + k];
    else if (r < 2048) v = Whh[(r-512)*512 + k];
    else               v = Wout[(size_t)(r-2048)*1024 + 512 + k];
    WALL[idx] = (__bf16)v;
  } else if (idx < 1572864) {
    int t = idx - 1310720;
    int n = t >> 9, k = t & 511;
    WC[t] = (__bf16)Wout[(size_t)n*1024 + k];
  } else {
    int t = idx - 1572864;
    WI[t] = (__bf16)Wih[t];
  }
}

__global__ __launch_bounds__(256) void h_init(
    const float* __restrict__ h0, float* __restrict__ h, bf16_t* __restrict__ hbf)
{
  int idx = blockIdx.x * 256 + threadIdx.x;   // 16384
  float v = h0[idx & 511];
  h[idx] = v;
  hbf[idx] = (__bf16)v;
}

__global__ __launch_bounds__(256) void lengths_kernel(
    const int* __restrict__ cpt, int* __restrict__ len)
{
  int r = blockIdx.x * 256 + threadIdx.x;
  if (r < 1536) {
    int c = 0;
    for (int s = 0; s < 64; ++s) c += (cpt[r*64 + s] != 0);
    len[r] = c > 1 ? c : 1;
  }
}

// ---- embed GEMM: mem[sent][b][s][h] = bf16(elu(emb_table[cpt]@W_eh^T + b)) ----
__global__ __launch_bounds__(256) void embed_gemm(
    const int* __restrict__ cpt, const float* __restrict__ table,
    const float* __restrict__ Weh, const float* __restrict__ beh,
    bf16_t* __restrict__ mem)
{
  __shared__ unsigned short A_lds[64][40];
  __shared__ unsigned short B_lds[64][40];
  const int bid = blockIdx.x;
  const int M0 = (bid >> 3) * 64;
  const int N0 = (bid & 7) * 64;
  const int tid = threadIdx.x, lane = tid & 63, w = tid >> 6;
  const int l15 = lane & 15, quad = lane >> 4;
  const int srow = tid >> 2;
  const int koff = (tid & 3) * 8;
  const int tok = cpt[M0 + srow];
  const float* arow = table + (size_t)tok * 512;
  const float* brow = Weh + (size_t)(N0 + srow) * 512;

  f32x4 acc0 = {0,0,0,0}, acc1 = {0,0,0,0}, acc2 = {0,0,0,0}, acc3 = {0,0,0,0};
  for (int kt = 0; kt < 16; ++kt) {
    const int k0 = kt * 32;
    float4 alo = *(const float4*)(arow + k0 + koff);
    float4 ahi = *(const float4*)(arow + k0 + koff + 4);
    float4 blo = *(const float4*)(brow + k0 + koff);
    float4 bhi = *(const float4*)(brow + k0 + koff + 4);
    __syncthreads();
    *(bf16x8*)(&A_lds[srow][koff]) = cvt8(alo, ahi);
    *(bf16x8*)(&B_lds[srow][koff]) = cvt8(blo, bhi);
    __syncthreads();
    const int kq = quad * 8;
    bf16x8 bfr = *(const bf16x8*)(&B_lds[16*w + l15][kq]);
    bf16x8 a0 = *(const bf16x8*)(&A_lds[l15][kq]);
    bf16x8 a1 = *(const bf16x8*)(&A_lds[16 + l15][kq]);
    bf16x8 a2 = *(const bf16x8*)(&A_lds[32 + l15][kq]);
    bf16x8 a3 = *(const bf16x8*)(&A_lds[48 + l15][kq]);
    acc0 = MFMA16(a0, bfr, acc0);
    acc1 = MFMA16(a1, bfr, acc1);
    acc2 = MFMA16(a2, bfr, acc2);
    acc3 = MFMA16(a3, bfr, acc3);
  }
  const int n = N0 + 16*w + l15;
  const float bias = beh[n];
  f32x4 accs[4] = {acc0, acc1, acc2, acc3};
  #pragma unroll
  for (int mt = 0; mt < 4; ++mt) {
    #pragma unroll
    for (int r = 0; r < 4; ++r) {
      int m = M0 + mt*16 + quad*4 + r;
      float v = accs[mt][r] + bias;
      v = v > 0.f ? v : expm1f(v);
      int s = m & 63, nrow = m >> 6;
      int sent = nrow % 48, b = nrow / 48;
      mem[(((size_t)(sent*32 + b))*64 + s)*512 + n] = (__bf16)v;
    }
  }
}

// ======================= 3-phase persistent scan (32 blocks) ================
// P1: all blocks GEMM 80 rows of WALL=[W_in;W_hh;Wh2] -> q(bf16)/gh/hw2
// P2: block g = attention for batch g: scores=q.mem, softmax, c -> cb (bf16)
// P3: every block: full x = tanh(c@WC^T + hw2) (redundant, cheap), then its
//     48-row gi slice (dims 16g..16g+15 x 3 gates) + GRU update of h slice.
__global__ __launch_bounds__(256) void scan3(
    const bf16_t* __restrict__ mem, const int* __restrict__ lengths,
    const bf16_t* __restrict__ WALL, const bf16_t* __restrict__ WC,
    const bf16_t* __restrict__ WI,
    const float* __restrict__ b_ih, const float* __restrict__ b_hh,
    bf16_t* __restrict__ q, float* __restrict__ gh, float* __restrict__ hw2,
    bf16_t* __restrict__ cb, float* __restrict__ h, bf16_t* __restrict__ hbf,
    unsigned* __restrict__ flags, float* __restrict__ out)
{
  // LDS: a_lds [32 rows x 1040B] @0      (hbf in P1 / cb in P3)
  //      x_lds [32 rows x 1040B] @33280  (x in P3)
  //      hsm f32[512] @66560; sc[64] @68608; al[64] @68864
  //      gi f32[48][33] @69120 (6336) -> total 75456
  __shared__ __align__(16) unsigned char smem[75456];
  char* a_lds = (char*)smem;
  char* x_lds = (char*)smem + 33280;
  float* hsm = (float*)(smem + 66560);
  float* sc_lds = (float*)(smem + 68608);
  float* al_lds = (float*)(smem + 68864);
  float* gi_lds = (float*)(smem + 69120);

  const int g = blockIdx.x, tid = threadIdx.x, lane = tid & 63, w = tid >> 6;
  const int quad = lane >> 4, l15 = lane & 15;
  unsigned ph = 0;

  for (int i = 0; i < 48; ++i) {
    // ============ P1: q | gh | hw2 = h @ [W_in;W_hh;Wh2]^T =================
    for (int it = 0; it < 16; ++it) {
      int c = tid + 256*it;               // 4096 chunks of 8B over hbf[32][512]
      int row = c >> 7, cc = c & 127;
      unsigned long long v = ld_a64(hbf + row*512 + cc*4);
      *(unsigned long long*)(a_lds + row*1040 + cc*8) = v;
    }
    __syncthreads();
    for (int t = w; t < 5; t += 4) {      // wave0: tiles 0,4; waves1-3: tile w
      const int R = 80*g + 16*t + l15;    // WALL row
      const bf16_t* wrow = WALL + (size_t)R * 512;
      f32x4 acc0 = {0,0,0,0}, acc1 = {0,0,0,0};
      #pragma unroll
      for (int kt = 0; kt < 16; ++kt) {
        const int k = kt*32 + quad*8;
        bf16x8 bfr = *(const bf16x8*)(wrow + k);
        bf16x8 a0 = *(const bf16x8*)(a_lds + l15*1040 + k*2);
        bf16x8 a1 = *(const bf16x8*)(a_lds + (16 + l15)*1040 + k*2);
        acc0 = MFMA16(a0, bfr, acc0);
        acc1 = MFMA16(a1, bfr, acc1);
      }
      if (R < 512) {
        #pragma unroll
        for (int r = 0; r < 4; ++r) {
          int b = quad*4 + r;
          st_b16(q + b*512 + R,        (__bf16)acc0[r]);
          st_b16(q + (b+16)*512 + R,   (__bf16)acc1[r]);
        }
      } else if (R < 2048) {
        const float bias = b_hh[R - 512];
        #pragma unroll
        for (int r = 0; r < 4; ++r) {
          int b = quad*4 + r;
          st_a32(gh + b*1536 + (R-512),      f2u(acc0[r] + bias));
          st_a32(gh + (b+16)*1536 + (R-512), f2u(acc1[r] + bias));
        }
      } else {
        #pragma unroll
        for (int r = 0; r < 4; ++r) {
          int b = quad*4 + r;
          st_a32(hw2 + b*512 + (R-2048),      f2u(acc0[r]));
          st_a32(hw2 + (b+16)*512 + (R-2048), f2u(acc1[r]));
        }
      }
    }
    gbar(flags, ++ph);

    // ============ P2: attention for batch g ================================
    {
      { unsigned v = ld_a32((const unsigned*)(q + g*512) + tid);
        float2 f = bf2f(v);
        hsm[2*tid] = f.x; hsm[2*tid + 1] = f.y; }
      __syncthreads();
      const bf16_t* mrow = mem + ((size_t)(i*32 + g)) * 64 * 512;
      {
        const int s = tid >> 2, p = tid & 3;
        const uint4* mp = (const uint4*)(mrow + s*512 + p*128);
        const float* qp = hsm + p*128;
        float sum = 0.f;
        #pragma unroll
        for (int it = 0; it < 16; ++it) {
          uint4 u = mp[it];
          float2 f0 = bf2f(u.x), f1 = bf2f(u.y), f2 = bf2f(u.z), f3 = bf2f(u.w);
          const float* qq = qp + it*8;
          sum += f0.x*qq[0] + f0.y*qq[1] + f1.x*qq[2] + f1.y*qq[3]
               + f2.x*qq[4] + f2.y*qq[5] + f3.x*qq[6] + f3.y*qq[7];
        }
        sum += __shfl_xor(sum, 1);
        sum += __shfl_xor(sum, 2);
        if (p == 0) {
          int len = lengths[g*48 + i];
          sc_lds[s] = (s < len) ? sum : -1e30f;
        }
      }
      __syncthreads();
      if (tid < 64) {
        float v = sc_lds[tid];
        float mx = v;
        #pragma unroll
        for (int o = 32; o; o >>= 1) mx = fmaxf(mx, __shfl_xor(mx, o));
        float e = __expf(v - mx);
        float sm = e;
        #pragma unroll
        for (int o = 32; o; o >>= 1) sm += __shfl_xor(sm, o);
        al_lds[tid] = e * __builtin_amdgcn_rcpf(sm);
      }
      __syncthreads();
      {
        const int d0 = tid * 2;
        float c0 = 0.f, c1 = 0.f;
        for (int s2 = 0; s2 < 64; ++s2) {
          unsigned u = *(const unsigned*)(mrow + s2*512 + d0);
          float2 f = bf2f(u);
          float a = al_lds[s2];
          c0 += a * f.x; c1 += a * f.y;
        }
        st_a32(cb + g*512 + d0, pack_bf2(c0, c1));
      }
    }
    gbar(flags, ++ph);

    // ============ P3: x = tanh(c@WC^T + hw2); gi slice; GRU ================
    for (int it = 0; it < 16; ++it) {
      int c = tid + 256*it;               // stage cb[32][512] bf16 -> a_lds
      int row = c >> 7, cc = c & 127;
      unsigned long long v = ld_a64(cb + row*512 + cc*4);
      *(unsigned long long*)(a_lds + row*1040 + cc*8) = v;
    }
    __syncthreads();
    {
      // cW GEMM: wave w covers n in [128w, 128w+128), 8 n-tiles, M=32
      f32x4 acc[2][8];
      #pragma unroll
      for (int mt = 0; mt < 2; ++mt)
        #pragma unroll
        for (int nt = 0; nt < 8; ++nt) acc[mt][nt] = (f32x4){0,0,0,0};
      #pragma unroll
      for (int kt = 0; kt < 16; ++kt) {
        const int k = kt*32 + quad*8;
        bf16x8 a0 = *(const bf16x8*)(a_lds + l15*1040 + k*2);
        bf16x8 a1 = *(const bf16x8*)(a_lds + (16 + l15)*1040 + k*2);
        #pragma unroll
        for (int nt = 0; nt < 8; ++nt) {
          const int n = 128*w + 16*nt + l15;
          bf16x8 bfr = *(const bf16x8*)(WC + (size_t)n*512 + k);
          acc[0][nt] = MFMA16(a0, bfr, acc[0][nt]);
          acc[1][nt] = MFMA16(a1, bfr, acc[1][nt]);
        }
      }
      #pragma unroll
      for (int nt = 0; nt < 8; ++nt) {
        const int n = 128*w + 16*nt + l15;
        #pragma unroll
        for (int mt = 0; mt < 2; ++mt) {
          #pragma unroll
          for (int r = 0; r < 4; ++r) {
            int b = 16*mt + quad*4 + r;
            float hv = u2f(ld_a32(hw2 + b*512 + n));
            float xv = ftanh(acc[mt][nt][r] + hv);
            *(unsigned short*)(x_lds + b*1040 + n*2) =
                __builtin_bit_cast(unsigned short, (__bf16)xv);
          }
        }
      }
    }
    __syncthreads();
    if (w < 3) {
      // gi GEMM: wave w = gate w; WI rows w*512 + 16g + l15
      const bf16_t* wrow = WI + ((size_t)(w*512 + 16*g + l15)) * 512;
      f32x4 ga0 = {0,0,0,0}, ga1 = {0,0,0,0};
      #pragma unroll
      for (int kt = 0; kt < 16; ++kt) {
        const int k = kt*32 + quad*8;
        bf16x8 bfr = *(const bf16x8*)(wrow + k);
        bf16x8 a0 = *(const bf16x8*)(x_lds + l15*1040 + k*2);
        bf16x8 a1 = *(const bf16x8*)(x_lds + (16 + l15)*1040 + k*2);
        ga0 = MFMA16(a0, bfr, ga0);
        ga1 = MFMA16(a1, bfr, ga1);
      }
      #pragma unroll
      for (int r = 0; r < 4; ++r) {
        gi_lds[(w*16 + l15)*33 + quad*4 + r]      = ga0[r];
        gi_lds[(w*16 + l15)*33 + 16 + quad*4 + r] = ga1[r];
      }
    }
    __syncthreads();
    #pragma unroll
    for (int half = 0; half < 2; ++half) {
      int item = tid + 256*half;            // 0..511 = 32 b x 16 d
      int b = item >> 4, d = item & 15;
      int D = 16*g + d;
      float ir = gi_lds[d*33 + b]        + b_ih[D];
      float iz = gi_lds[(16+d)*33 + b]   + b_ih[512 + D];
      float in = gi_lds[(32+d)*33 + b]   + b_ih[1024 + D];
      float hr = u2f(ld_a32(gh + b*1536 + D));
      float hz = u2f(ld_a32(gh + b*1536 + 512 + D));
      float hn = u2f(ld_a32(gh + b*1536 + 1024 + D));
      float ho = u2f(ld_a32(h + b*512 + D));
      float rr = fsig(ir + hr);
      float zz = fsig(iz + hz);
      float nn = ftanh(in + rr * hn);
      float res = (1.f - zz) * nn + zz * ho;
      if (i == 47) {
        out[b*512 + D] = res;
      } else {
        st_a32(h + b*512 + D, f2u(res));
        st_b16(hbf + b*512 + D, (__bf16)res);
      }
    }
    gbar(flags, ++ph);
  }
}

// ---------------------------------------------------------------------------
extern "C" void kernel_launch(void* const* d_in, const int* in_sizes, int n_in,
                              void* d_out, int out_size, void* d_ws, size_t ws_size,
                              hipStream_t stream) {
  const int*   cpt   = (const int*)d_in[0];
  const float* table = (const float*)d_in[2];
  const float* Weh   = (const float*)d_in[3];
  const float* beh   = (const float*)d_in[4];
  const float* h0    = (const float*)d_in[5];
  const float* Win   = (const float*)d_in[6];
  const float* Wout  = (const float*)d_in[7];
  const float* Wih   = (const float*)d_in[8];
  const float* Whh   = (const float*)d_in[9];
  const float* bih   = (const float*)d_in[10];
  const float* bhh   = (const float*)d_in[11];

  if (ws_size < WS_NEED) return;

  char* ws = (char*)d_ws;
  bf16_t* mem  = (bf16_t*)(ws + OFF_MEM);
  bf16_t* WALL = (bf16_t*)(ws + OFF_WALL);
  bf16_t* WC   = (bf16_t*)(ws + OFF_WC);
  bf16_t* WI   = (bf16_t*)(ws + OFF_WI);
  int*    len  = (int*)(ws + OFF_LEN);
  float*  h    = (float*)(ws + OFF_H);
  bf16_t* hbf  = (bf16_t*)(ws + OFF_HBF);
  bf16_t* q    = (bf16_t*)(ws + OFF_Q);
  float*  gh   = (float*)(ws + OFF_GH);
  float*  hw2  = (float*)(ws + OFF_HW2);
  bf16_t* cb   = (bf16_t*)(ws + OFF_CB);
  unsigned* flg = (unsigned*)(ws + OFF_FLG);

  hipMemsetAsync(flg, 0, 128, stream);
  prep_weights<<<9216, 256, 0, stream>>>(Win, Whh, Wout, Wih, WALL, WC, WI);
  h_init<<<64, 256, 0, stream>>>(h0, h, hbf);
  lengths_kernel<<<6, 256, 0, stream>>>(cpt, len);
  embed_gemm<<<12288, 256, 0, stream>>>(cpt, table, Weh, beh, mem);
  scan3<<<32, 256, 0, stream>>>(mem, len, WALL, WC, WI, bih, bhh,
                                q, gh, hw2, cb, h, hbf, flg, (float*)d_out);
}

// Round 5
// 2589.523 us; speedup vs baseline: 1.2859x; 1.2859x over previous
//
#include <hip/hip_runtime.h>
#include <hip/hip_bf16.h>
#include <stdint.h>

// ---------------------------------------------------------------------------
// GraphEncoder. Round 5: BARRIER-FREE scan. The 32 batch recurrences are
// independent -> block g owns batch g entirely; h state lives in LDS; all
// per-step GEMVs via v_dot2_f32_f16 against fp16 weights in a k-blocked
// coalesced layout [kq][N][4]. No grid sync, no device atomics.
// ---------------------------------------------------------------------------

typedef __bf16 bf16_t;
typedef __bf16 bf16x8 __attribute__((ext_vector_type(8)));
typedef float  f32x4  __attribute__((ext_vector_type(4)));
typedef _Float16 f16;
typedef _Float16 f16x2 __attribute__((ext_vector_type(2)));

#define MFMA16(a,b,c) __builtin_amdgcn_mfma_f32_16x16x32_bf16((a),(b),(c),0,0,0)

// ---- workspace layout (bytes) ----
static constexpr size_t OFF_MEM   = 0;                      // f16 [1536][64][512] = 100,663,296
static constexpr size_t OFF_WALLT = 100663296;              // u32 [64][2560][4]   = 2,621,440
static constexpr size_t OFF_WCT   = OFF_WALLT + 2621440;    // u32 [64][512][4]    = 524,288
static constexpr size_t OFF_WIT   = OFF_WCT + 524288;       // u32 [64][1536][4]   = 1,572,864
static constexpr size_t OFF_LEN   = OFF_WIT + 1572864;      // int [1536]
static constexpr size_t WS_NEED   = OFF_LEN + 8192;         // 105,390,080

// ---- helpers ----
__device__ __forceinline__ float dot2(unsigned w, unsigned x, float acc) {
#if __has_builtin(__builtin_amdgcn_fdot2)
  return __builtin_amdgcn_fdot2(__builtin_bit_cast(f16x2, w),
                                __builtin_bit_cast(f16x2, x), acc, false);
#else
  f16x2 wv = __builtin_bit_cast(f16x2, w);
  f16x2 xv = __builtin_bit_cast(f16x2, x);
  return acc + (float)wv[0]*(float)xv[0] + (float)wv[1]*(float)xv[1];
#endif
}
__device__ __forceinline__ unsigned pack_h2(float a, float b) {
  f16 ha = (f16)a, hb = (f16)b;
  unsigned short ua = __builtin_bit_cast(unsigned short, ha);
  unsigned short ub = __builtin_bit_cast(unsigned short, hb);
  return (unsigned)ua | ((unsigned)ub << 16);
}
__device__ __forceinline__ bf16x8 cvt8(float4 lo, float4 hi) {
  bf16x8 v;
  v[0]=(__bf16)lo.x; v[1]=(__bf16)lo.y; v[2]=(__bf16)lo.z; v[3]=(__bf16)lo.w;
  v[4]=(__bf16)hi.x; v[5]=(__bf16)hi.y; v[6]=(__bf16)hi.z; v[7]=(__bf16)hi.w;
  return v;
}
__device__ __forceinline__ float fsig(float x) {
  return __builtin_amdgcn_rcpf(1.f + __expf(-x));
}
__device__ __forceinline__ float ftanh(float x) {
  float e = __expf(-2.f * fabsf(x));
  float t = (1.f - e) * __builtin_amdgcn_rcpf(1.f + e);
  return __builtin_copysignf(t, x);
}

// ======================= prep kernels ======================================
// Weight layouts for GEMV: flat[(kq*N + n)*4 + j] packs f16 pair k = 8*kq+2*j
// of logical row n. Coalesced uint4 loads: lane n reads 16B = 4 k2-pairs.
__global__ __launch_bounds__(256) void prep_w(
    const float* __restrict__ Win, const float* __restrict__ Whh,
    const float* __restrict__ Wout, const float* __restrict__ Wih,
    unsigned* __restrict__ WALLT, unsigned* __restrict__ WCT,
    unsigned* __restrict__ WIT)
{
  int t = blockIdx.x * 256 + threadIdx.x;   // 1,179,648 total u32s
  if (t < 655360) {                          // WALLT: N=2560
    int kq = t / 10240, rem = t - kq * 10240;
    int n = rem >> 2, j = rem & 3;
    int k = 8*kq + 2*j;
    float a, b;
    if (n < 512)       { a = Win[n*512 + k];        b = Win[n*512 + k + 1]; }
    else if (n < 2048) { a = Whh[(n-512)*512 + k];  b = Whh[(n-512)*512 + k + 1]; }
    else               { a = Wout[(size_t)(n-2048)*1024 + 512 + k];
                         b = Wout[(size_t)(n-2048)*1024 + 513 + k]; }
    WALLT[t] = pack_h2(a, b);
  } else if (t < 786432) {                   // WCT: N=512
    int u = t - 655360;
    int kq = u / 2048, rem = u - kq * 2048;
    int n = rem >> 2, j = rem & 3;
    int k = 8*kq + 2*j;
    WCT[u] = pack_h2(Wout[(size_t)n*1024 + k], Wout[(size_t)n*1024 + k + 1]);
  } else {                                   // WIT: N=1536
    int u = t - 786432;
    int kq = u / 6144, rem = u - kq * 6144;
    int n = rem >> 2, j = rem & 3;
    int k = 8*kq + 2*j;
    WIT[u] = pack_h2(Wih[n*512 + k], Wih[n*512 + k + 1]);
  }
}

__global__ __launch_bounds__(256) void lengths_kernel(
    const int* __restrict__ cpt, int* __restrict__ len)
{
  int r = blockIdx.x * 256 + threadIdx.x;
  if (r < 1536) {
    int c = 0;
    for (int s = 0; s < 64; ++s) c += (cpt[r*64 + s] != 0);
    len[r] = c > 1 ? c : 1;
  }
}

// ---- embed GEMM: mem[sent][b][s][h] = f16(elu(emb_table[cpt]@W_eh^T + b)) ----
__global__ __launch_bounds__(256) void embed_gemm(
    const int* __restrict__ cpt, const float* __restrict__ table,
    const float* __restrict__ Weh, const float* __restrict__ beh,
    f16* __restrict__ mem)
{
  __shared__ unsigned short A_lds[64][40];
  __shared__ unsigned short B_lds[64][40];
  const int bid = blockIdx.x;
  const int M0 = (bid >> 3) * 64;
  const int N0 = (bid & 7) * 64;
  const int tid = threadIdx.x, lane = tid & 63, w = tid >> 6;
  const int l15 = lane & 15, quad = lane >> 4;
  const int srow = tid >> 2;
  const int koff = (tid & 3) * 8;
  const int tok = cpt[M0 + srow];
  const float* arow = table + (size_t)tok * 512;
  const float* brow = Weh + (size_t)(N0 + srow) * 512;

  f32x4 acc0 = {0,0,0,0}, acc1 = {0,0,0,0}, acc2 = {0,0,0,0}, acc3 = {0,0,0,0};
  for (int kt = 0; kt < 16; ++kt) {
    const int k0 = kt * 32;
    float4 alo = *(const float4*)(arow + k0 + koff);
    float4 ahi = *(const float4*)(arow + k0 + koff + 4);
    float4 blo = *(const float4*)(brow + k0 + koff);
    float4 bhi = *(const float4*)(brow + k0 + koff + 4);
    __syncthreads();
    *(bf16x8*)(&A_lds[srow][koff]) = cvt8(alo, ahi);
    *(bf16x8*)(&B_lds[srow][koff]) = cvt8(blo, bhi);
    __syncthreads();
    const int kq = quad * 8;
    bf16x8 bfr = *(const bf16x8*)(&B_lds[16*w + l15][kq]);
    bf16x8 a0 = *(const bf16x8*)(&A_lds[l15][kq]);
    bf16x8 a1 = *(const bf16x8*)(&A_lds[16 + l15][kq]);
    bf16x8 a2 = *(const bf16x8*)(&A_lds[32 + l15][kq]);
    bf16x8 a3 = *(const bf16x8*)(&A_lds[48 + l15][kq]);
    acc0 = MFMA16(a0, bfr, acc0);
    acc1 = MFMA16(a1, bfr, acc1);
    acc2 = MFMA16(a2, bfr, acc2);
    acc3 = MFMA16(a3, bfr, acc3);
  }
  const int n = N0 + 16*w + l15;
  const float bias = beh[n];
  f32x4 accs[4] = {acc0, acc1, acc2, acc3};
  #pragma unroll
  for (int mt = 0; mt < 4; ++mt) {
    #pragma unroll
    for (int r = 0; r < 4; ++r) {
      int m = M0 + mt*16 + quad*4 + r;
      float v = accs[mt][r] + bias;
      v = v > 0.f ? v : expm1f(v);
      int s = m & 63, nrow = m >> 6;
      int sent = nrow % 48, b = nrow / 48;
      mem[(((size_t)(sent*32 + b))*64 + s)*512 + n] = (f16)v;
    }
  }
}

// ======================= barrier-free per-batch scan ========================
// 32 blocks x 512 threads. Block g = batch g; 48 sequential steps, all state
// in LDS, only global reads are static (mem slice, weights, biases, len).
__global__ __launch_bounds__(512, 1) void scan_local(
    const f16* __restrict__ mem, const int* __restrict__ len,
    const unsigned* __restrict__ WALLT, const unsigned* __restrict__ WCT,
    const unsigned* __restrict__ WIT,
    const float* __restrict__ b_ih, const float* __restrict__ b_hh,
    const float* __restrict__ h0, float* __restrict__ out)
{
  __shared__ __align__(16) f16 mem_s[64][520];     // 66,560 B (1040 B rows)
  __shared__ __align__(16) unsigned qh[256];        // q packed f16x2
  __shared__ __align__(16) f16 c2h[512];            // context c (f16)
  __shared__ __align__(16) f16 x2h[512];            // x (f16)
  __shared__ __align__(16) f16 h2h[512];            // h (f16, S1 operand)
  __shared__ float hf[512];                          // h (f32, GRU state)
  __shared__ float z[2560];                          // S1 out: q|gh|hw2
  __shared__ float sc[64], al[64];
  __shared__ float bih_s[1536], bhh_s[1536];

  const int g = blockIdx.x, tid = threadIdx.x;
  const unsigned* h2u = (const unsigned*)h2h;
  const unsigned* c2u = (const unsigned*)c2h;
  const unsigned* x2u = (const unsigned*)x2h;

  // prologue: stage biases + h0
  #pragma unroll
  for (int it = 0; it < 3; ++it) {
    int idx = tid + 512*it;
    bih_s[idx] = b_ih[idx];
    bhh_s[idx] = b_hh[idx];
  }
  { float v = h0[tid]; hf[tid] = v; h2h[tid] = (f16)v; }
  __syncthreads();

  for (int i = 0; i < 48; ++i) {
    const int L = len[g*48 + i];
    // ---- (0) stage mem slice [64][512] f16 -> LDS (coalesced uint4) -------
    {
      const f16* src = mem + ((size_t)(i*32 + g)) * 64 * 512;
      #pragma unroll
      for (int it = 0; it < 8; ++it) {
        int c = tid + 512*it;             // 4096 chunks of 16B
        int s = c >> 6, q4 = c & 63;
        uint4 v = *(const uint4*)(src + (size_t)s*512 + q4*8);
        *(uint4*)(&mem_s[s][q4*8]) = v;
      }
    }
    // ---- (1) S1: z[0:2560] = [W_in; W_hh; Wh2] . h  (fdot2 GEMV) ----------
    {
      float acc[5] = {0.f, 0.f, 0.f, 0.f, 0.f};
      for (int kq = 0; kq < 64; ++kq) {
        uint4 h4 = *(const uint4*)(h2u + kq*4);
        #pragma unroll
        for (int j = 0; j < 5; ++j) {
          const int n = tid + 512*j;
          uint4 w = *(const uint4*)(WALLT + ((size_t)kq*2560 + n)*4);
          acc[j] = dot2(w.x, h4.x, acc[j]);
          acc[j] = dot2(w.y, h4.y, acc[j]);
          acc[j] = dot2(w.z, h4.z, acc[j]);
          acc[j] = dot2(w.w, h4.w, acc[j]);
        }
      }
      // n = tid is the q row -> store packed f16 for the score dot
      { f16 qv = (f16)acc[0];
        *((unsigned short*)qh + tid) = __builtin_bit_cast(unsigned short, qv); }
      #pragma unroll
      for (int j = 1; j < 5; ++j) z[tid + 512*j] = acc[j];
    }
    __syncthreads();

    // ---- (2) scores + softmax ---------------------------------------------
    {
      const int s = tid >> 3, p = tid & 7;
      const unsigned* mrow = (const unsigned*)(&mem_s[s][0]) + p*32;
      const unsigned* qrow = qh + p*32;
      float sum = 0.f;
      #pragma unroll
      for (int k = 0; k < 32; ++k) sum = dot2(mrow[k], qrow[k], sum);
      sum += __shfl_xor(sum, 1);
      sum += __shfl_xor(sum, 2);
      sum += __shfl_xor(sum, 4);
      if (p == 0) sc[s] = (s < L) ? sum : -1e30f;
    }
    __syncthreads();
    if (tid < 64) {
      float v = sc[tid];
      float mx = v;
      #pragma unroll
      for (int o = 32; o; o >>= 1) mx = fmaxf(mx, __shfl_xor(mx, o));
      float e = __expf(v - mx);
      float sm = e;
      #pragma unroll
      for (int o = 32; o; o >>= 1) sm += __shfl_xor(sm, o);
      al[tid] = e * __builtin_amdgcn_rcpf(sm);
    }
    __syncthreads();

    // ---- (3) context c[d] = sum_s al[s] * mem_s[s][d] ----------------------
    {
      float cacc = 0.f;
      #pragma unroll 8
      for (int s = 0; s < 64; ++s) cacc += al[s] * (float)mem_s[s][tid];
      c2h[tid] = (f16)cacc;
    }
    __syncthreads();

    // ---- (4) x[n] = tanh(c . WC[n] + hw2[n]) -------------------------------
    {
      float acc = z[2048 + tid];
      for (int kq = 0; kq < 64; ++kq) {
        uint4 c4 = *(const uint4*)(c2u + kq*4);
        uint4 w = *(const uint4*)(WCT + ((size_t)kq*512 + tid)*4);
        acc = dot2(w.x, c4.x, acc);
        acc = dot2(w.y, c4.y, acc);
        acc = dot2(w.z, c4.z, acc);
        acc = dot2(w.w, c4.w, acc);
      }
      x2h[tid] = (f16)ftanh(acc);
    }
    __syncthreads();

    // ---- (5) gi = x . W_ih^T (3 gates) + GRU update ------------------------
    {
      float a0 = 0.f, a1 = 0.f, a2 = 0.f;
      for (int kq = 0; kq < 64; ++kq) {
        uint4 x4 = *(const uint4*)(x2u + kq*4);
        const unsigned* wb = WIT + (size_t)kq*6144;
        uint4 w0 = *(const uint4*)(wb + (tid)*4);
        uint4 w1 = *(const uint4*)(wb + (tid + 512)*4);
        uint4 w2 = *(const uint4*)(wb + (tid + 1024)*4);
        a0 = dot2(w0.x, x4.x, a0); a0 = dot2(w0.y, x4.y, a0);
        a0 = dot2(w0.z, x4.z, a0); a0 = dot2(w0.w, x4.w, a0);
        a1 = dot2(w1.x, x4.x, a1); a1 = dot2(w1.y, x4.y, a1);
        a1 = dot2(w1.z, x4.z, a1); a1 = dot2(w1.w, x4.w, a1);
        a2 = dot2(w2.x, x4.x, a2); a2 = dot2(w2.y, x4.y, a2);
        a2 = dot2(w2.z, x4.z, a2); a2 = dot2(w2.w, x4.w, a2);
      }
      const int d = tid;
      float ir = a0 + bih_s[d];
      float iz = a1 + bih_s[512 + d];
      float in = a2 + bih_s[1024 + d];
      float hr = z[512 + d]  + bhh_s[d];
      float hz = z[1024 + d] + bhh_s[512 + d];
      float hn = z[1536 + d] + bhh_s[1024 + d];
      float ho = hf[d];
      float rr = fsig(ir + hr);
      float zz = fsig(iz + hz);
      float nn = ftanh(in + rr * hn);
      float res = (1.f - zz) * nn + zz * ho;
      if (i == 47) {
        out[g*512 + d] = res;
      } else {
        hf[d] = res;
        h2h[d] = (f16)res;
      }
    }
    __syncthreads();
  }
}

// ---------------------------------------------------------------------------
extern "C" void kernel_launch(void* const* d_in, const int* in_sizes, int n_in,
                              void* d_out, int out_size, void* d_ws, size_t ws_size,
                              hipStream_t stream) {
  const int*   cpt   = (const int*)d_in[0];
  const float* table = (const float*)d_in[2];
  const float* Weh   = (const float*)d_in[3];
  const float* beh   = (const float*)d_in[4];
  const float* h0    = (const float*)d_in[5];
  const float* Win   = (const float*)d_in[6];
  const float* Wout  = (const float*)d_in[7];
  const float* Wih   = (const float*)d_in[8];
  const float* Whh   = (const float*)d_in[9];
  const float* bih   = (const float*)d_in[10];
  const float* bhh   = (const float*)d_in[11];

  if (ws_size < WS_NEED) return;

  char* ws = (char*)d_ws;
  f16*      mem   = (f16*)(ws + OFF_MEM);
  unsigned* WALLT = (unsigned*)(ws + OFF_WALLT);
  unsigned* WCT   = (unsigned*)(ws + OFF_WCT);
  unsigned* WIT   = (unsigned*)(ws + OFF_WIT);
  int*      len   = (int*)(ws + OFF_LEN);

  prep_w<<<4608, 256, 0, stream>>>(Win, Whh, Wout, Wih, WALLT, WCT, WIT);
  lengths_kernel<<<6, 256, 0, stream>>>(cpt, len);
  embed_gemm<<<12288, 256, 0, stream>>>(cpt, table, Weh, beh, mem);
  scan_local<<<32, 512, 0, stream>>>(mem, len, WALLT, WCT, WIT,
                                     bih, bhh, h0, (float*)d_out);
}